// Round 9
// baseline (30.009 us; speedup 1.0000x reference)
//
#include <hip/hip_runtime.h>

typedef _Float16 f16;
typedef __attribute__((ext_vector_type(2))) _Float16 f16x2;
typedef __attribute__((ext_vector_type(4))) _Float16 f16x4;
typedef __attribute__((ext_vector_type(8))) _Float16 f16x8;
typedef __attribute__((ext_vector_type(4))) float f32x4;
typedef __attribute__((ext_vector_type(4))) unsigned u32x4;

constexpr int IN_F  = 4096;
constexpr int OUT_F = 11008;
constexpr int NGRP  = 32;     // 4096 / 128
constexpr int NTILE = OUT_F / 16;   // 688

// dequant one byte-holding int32 (2 nibbles) -> 2 packed f16 weights
__device__ __forceinline__ unsigned dq2(unsigned q, f16x2 sp, f16x2 zp) {
    unsigned t = (((q << 12) | q) & 0x000F000Fu) | 0x64006400u;  // (1024+lo, 1024+hi)
    f16x2 u = __builtin_bit_cast(f16x2, t);
    u = u - (f16x2){(_Float16)1024.0f, (_Float16)1024.0f};       // exact
    u = u * sp + zp;                                             // v_pk_fma_f16
    return __builtin_bit_cast(unsigned, u);
}

__device__ __forceinline__ f16x2 bcast(float v) {
    _Float16 h = (_Float16)v;
    return (f16x2){h, h};
}

// x [8][4096] f32 -> f16 workspace
__global__ void xprep_kernel(const float* __restrict__ x, f16* __restrict__ xh) {
    int i = (blockIdx.x * blockDim.x + threadIdx.x) * 4;
    float4 v = *(const float4*)(x + i);
    f16x4 r = {(f16)v.x, (f16)v.y, (f16)v.z, (f16)v.w};
    *(f16x4*)(xh + i) = r;
}

// 5504 blocks = 688 tiles x 8 k-slabs; 4 waves/block, each wave owns one
// 128-k slab (= one quant group, 4KB weights). Wave: 4 global_load_lds +
// 4 f16x8 x-loads + s/z, ONE vmcnt(0), 4 MFMA, alias-reduce, atomicAdd.
// LDS 16KB, launch_bounds(256,6) -> 24 waves/CU.
__global__ __launch_bounds__(256, 6)
void qlin_atomic(const int* __restrict__ wq,
                 const float* __restrict__ scales,
                 const float* __restrict__ zeros,
                 const float* __restrict__ bias,
                 const f16* __restrict__ xh,
                 float* __restrict__ out)
{
    __shared__ unsigned char wlds[16384];   // 4 waves x 4KB; reused for reduce

    const int tid  = threadIdx.x;
    const int wv   = tid >> 6;
    const int lane = tid & 63;
    const int col  = lane & 15;      // weight row in tile / MFMA n; A row m
    const int kg   = lane >> 4;      // k quarter within 32-k tile
    const int bid  = blockIdx.x;
    const int ot   = bid >> 3;       // output tile
    const int ks   = bid & 7;        // 512-k slab of the block
    const int o0   = ot * 16;
    const int orow = o0 + col;
    const int k0   = ks * 512 + wv * 128;    // this wave's 128-k slab
    const int g    = k0 >> 7;                // its (single) quant group
    const bool mvalid = (col < 8);

    // ---- stage 4KB of weights: 4 insts, 4 rows x 256B each, src swizzled ----
    const char* wb = (const char*)wq;
    #pragma unroll
    for (int c = 0; c < 4; ++c) {
        const int r = c * 4 + (lane >> 4);
        const char* src = wb + (size_t)(o0 + r) * 8192 + (size_t)k0 * 2
                          + (((lane & 15) * 16) ^ ((r & 7) << 4));
        __builtin_amdgcn_global_load_lds(
            (const __attribute__((address_space(1))) void*)src,
            (__attribute__((address_space(3))) void*)&wlds[wv * 4096 + c * 1024],
            16, 0, 0);
    }

    // ---- x fragments (f16, L2-hot) ----
    f16x8 af[4];
    if (mvalid) {
        const f16* xp = xh + (size_t)col * IN_F + k0 + kg * 8;
        #pragma unroll
        for (int t = 0; t < 4; ++t) af[t] = *(const f16x8*)(xp + t * 32);
    } else {
        #pragma unroll
        for (int t = 0; t < 4; ++t) af[t] = (f16x8){0,0,0,0,0,0,0,0};
    }

    const f16x2 s2 = bcast(scales[(size_t)orow * NGRP + g]);
    const f16x2 z2 = bcast(zeros [(size_t)orow * NGRP + g]);

    asm volatile("s_waitcnt vmcnt(0)" ::: "memory");
    __builtin_amdgcn_sched_barrier(0);

    // ---- compute: 4 k-tiles of 32 ----
    const unsigned swz  = (unsigned)((col & 7) << 4);
    const unsigned base = (unsigned)(wv * 4096 + col * 256);
    f32x4 acc = {0.f, 0.f, 0.f, 0.f};
    #pragma unroll
    for (int t = 0; t < 4; ++t) {
        const unsigned off = base + (((unsigned)(t * 64 + kg * 16)) ^ swz);
        const int4 q = *(const int4*)&wlds[off];
        u32x4 bw = {dq2((unsigned)q.x, s2, z2),
                    dq2((unsigned)q.y, s2, z2),
                    dq2((unsigned)q.z, s2, z2),
                    dq2((unsigned)q.w, s2, z2)};
        f16x8 bfr = __builtin_bit_cast(f16x8, bw);
        acc = __builtin_amdgcn_mfma_f32_16x16x32_f16(af[t], bfr, acc, 0, 0, 0);
    }

    // ---- cross-wave reduce (red aliased into own weight chunk) ----
    *(f32x4*)&wlds[wv * 4096 + lane * 16] = acc;
    __syncthreads();

    if (tid < 32) {   // rows 0..7 only: mbase = (tid>>4)*4 in {0,4}
        f32x4 ssum = *(const f32x4*)&wlds[tid * 16];
        #pragma unroll
        for (int w = 1; w < 4; ++w)
            ssum += *(const f32x4*)&wlds[w * 4096 + tid * 16];
        const int n = tid & 15;
        const int mbase = (tid >> 4) * 4;
        const float bb = (ks == 0) ? bias[o0 + n] : 0.f;
        #pragma unroll
        for (int i = 0; i < 4; ++i)
            atomicAdd(&out[(size_t)(mbase + i) * OUT_F + o0 + n], ssum[i] + bb);
    }
}

// ---------------- fallback (R5-style, used only if ws too small) ------------
__global__ __launch_bounds__(256, 4)
void qlin_kernel(const int* __restrict__ wq,
                 const float* __restrict__ scales,
                 const float* __restrict__ zeros,
                 const float* __restrict__ bias,
                 const float* __restrict__ xf,
                 float* __restrict__ out)
{
    __shared__ unsigned char wlds[2][16][1024];
    __shared__ f32x4 red[4][64];

    const int tid  = threadIdx.x;
    const int wv   = tid >> 6;
    const int lane = tid & 63;
    const int col  = lane & 15;
    const int kg   = lane >> 4;
    const int o0   = blockIdx.x * 16;
    const int orow = o0 + col;
    const bool mvalid = (col < 8);

    f16x2 sp[8], zp[8];
    #pragma unroll
    for (int s = 0; s < 8; ++s) {
        sp[s] = bcast(scales[(size_t)orow * NGRP + s * 4 + wv]);
        zp[s] = bcast(zeros [(size_t)orow * NGRP + s * 4 + wv]);
    }

    const char* wtile = (const char*)wq + (size_t)o0 * 8192;
    auto stage = [&](int sl, int bufi) {
        #pragma unroll
        for (int c = 0; c < 4; ++c) {
            const int r = 4 * wv + c;
            const char* src = wtile + (size_t)r * 8192 + sl * 1024
                              + ((lane * 16) ^ ((r & 7) << 4));
            __builtin_amdgcn_global_load_lds(
                (const __attribute__((address_space(1))) void*)src,
                (__attribute__((address_space(3))) void*)&wlds[bufi][r][0],
                16, 0, 0);
        }
    };

    stage(0, 0);
    stage(1, 1);

    const float* xfcol = xf + (size_t)col * IN_F;
    const unsigned swz = (unsigned)((col & 7) << 4);
    f32x4 acc = {0.f, 0.f, 0.f, 0.f};

    #pragma unroll
    for (int s = 0; s < 8; ++s) {
        asm volatile("s_waitcnt vmcnt(0)" ::: "memory");
        __builtin_amdgcn_s_barrier();
        asm volatile("" ::: "memory");

        const f16x2 s2 = sp[s], z2 = zp[s];
        #pragma unroll
        for (int t = 0; t < 4; ++t) {
            const int k = s * 512 + wv * 128 + t * 32 + kg * 8;
            f16x8 af = (f16x8){0,0,0,0,0,0,0,0};
            if (mvalid) {
                float4 a0 = *(const float4*)(xfcol + k);
                float4 a1 = *(const float4*)(xfcol + k + 4);
                af = (f16x8){(f16)a0.x,(f16)a0.y,(f16)a0.z,(f16)a0.w,
                             (f16)a1.x,(f16)a1.y,(f16)a1.z,(f16)a1.w};
            }
            const unsigned off = ((unsigned)(wv * 256 + t * 64 + kg * 16)) ^ swz;
            const int4 q = *(const int4*)&wlds[s & 1][col][off];
            u32x4 bw = {dq2((unsigned)q.x, s2, z2),
                        dq2((unsigned)q.y, s2, z2),
                        dq2((unsigned)q.z, s2, z2),
                        dq2((unsigned)q.w, s2, z2)};
            f16x8 bfr = __builtin_bit_cast(f16x8, bw);
            acc = __builtin_amdgcn_mfma_f32_16x16x32_f16(af, bfr, acc, 0, 0, 0);
        }

        asm volatile("" ::: "memory");
        __builtin_amdgcn_s_barrier();
        if (s < 6) stage(s + 2, s & 1);
    }

    red[wv][lane] = acc;
    __syncthreads();

    if (tid < 64) {
        f32x4 ssum = red[0][tid];
        #pragma unroll
        for (int w = 1; w < 4; ++w) ssum += red[w][tid];
        const int n = tid & 15;
        const float bb = bias[o0 + n];
        const int mbase = (tid >> 4) * 4;
        if (mbase < 8) {
            #pragma unroll
            for (int i = 0; i < 4; ++i)
                out[(size_t)(mbase + i) * OUT_F + o0 + n] = ssum[i] + bb;
        }
    }
}

extern "C" void kernel_launch(void* const* d_in, const int* in_sizes, int n_in,
                              void* d_out, int out_size, void* d_ws, size_t ws_size,
                              hipStream_t stream) {
    const float* x  = (const float*)d_in[0];
    const int*   wq = (const int*)d_in[1];
    const float* sc = (const float*)d_in[2];
    const float* zr = (const float*)d_in[3];
    const float* bs = (const float*)d_in[4];
    float* out = (float*)d_out;
    (void)in_sizes; (void)n_in;

    if (ws_size >= (size_t)(8 * IN_F * sizeof(f16))) {
        f16* xh = (f16*)d_ws;
        hipMemsetAsync(out, 0, (size_t)out_size * sizeof(float), stream);
        xprep_kernel<<<(8 * IN_F) / (256 * 4), 256, 0, stream>>>(x, xh);
        qlin_atomic<<<NTILE * 8, 256, 0, stream>>>(wq, sc, zr, bs, xh, out);
    } else {
        qlin_kernel<<<NTILE, 256, 0, stream>>>(wq, sc, zr, bs, x, out);
    }
}

// Round 11
// 28.801 us; speedup vs baseline: 1.0419x; 1.0419x over previous
//
#include <hip/hip_runtime.h>

typedef _Float16 f16;
typedef __attribute__((ext_vector_type(2))) _Float16 f16x2;
typedef __attribute__((ext_vector_type(4))) _Float16 f16x4;
typedef __attribute__((ext_vector_type(8))) _Float16 f16x8;
typedef __attribute__((ext_vector_type(4))) float f32x4;
typedef __attribute__((ext_vector_type(4))) unsigned u32x4;

constexpr int IN_F  = 4096;
constexpr int OUT_F = 11008;
constexpr int NGRP  = 32;            // 4096 / 128
constexpr int NTILE = OUT_F / 16;    // 688
constexpr int PLANE = OUT_F * 8;     // floats per split-K partial plane

// dequant one byte-holding int32 (2 nibbles) -> 2 packed f16 weights
__device__ __forceinline__ unsigned dq2(unsigned q, f16x2 sp, f16x2 zp) {
    unsigned t = (((q << 12) | q) & 0x000F000Fu) | 0x64006400u;  // (1024+lo, 1024+hi)
    f16x2 u = __builtin_bit_cast(f16x2, t);
    u = u - (f16x2){(_Float16)1024.0f, (_Float16)1024.0f};       // exact
    u = u * sp + zp;                                             // v_pk_fma_f16
    return __builtin_bit_cast(unsigned, u);
}

__device__ __forceinline__ f16x2 bcast(float v) {
    _Float16 h = (_Float16)v;
    return (f16x2){h, h};
}

// x [8][4096] f32 -> f16 workspace
__global__ void xprep_kernel(const float* __restrict__ x, f16* __restrict__ xh) {
    int i = (blockIdx.x * blockDim.x + threadIdx.x) * 4;
    float4 v = *(const float4*)(x + i);
    f16x4 r = {(f16)v.x, (f16)v.y, (f16)v.z, (f16)v.w};
    *(f16x4*)(xh + i) = r;
}

// 2752 blocks (688 o-tiles x 4 split-K) x 4 waves. Wave = private 256-k slab,
// 4 sub-slabs of 64k, weights double-buffered in private 2x2KB LDS.
// x fragments: af[4][2] distinct registers (NO aliasing — R10's WAR bug),
// loaded up-front; compiler tracks their deps. Weights-only counted FIFO:
// 2 global_load_lds per stage, vmcnt(2) between sub-slabs, zero barriers
// until the final cross-wave reduce. Both-sides XOR swizzle ^((row&7)<<4).
// launch_bounds(256,4): 128-VGPR class — no scratch spills (spills are vmem
// ops and would corrupt the counted vmcnt discipline).
__global__ __launch_bounds__(256, 4)
void qlin_pipe(const int* __restrict__ wq,
               const float* __restrict__ scales,
               const float* __restrict__ zeros,
               const f16* __restrict__ xh,
               float* __restrict__ wsf)
{
    __shared__ unsigned char wlds[4][2][2048];   // 16 KB: wave x dbuf x 2KB

    const int tid  = threadIdx.x;
    const int wv   = tid >> 6;
    const int lane = tid & 63;
    const int col  = lane & 15;      // weight row in tile / MFMA n; A row m
    const int kg   = lane >> 4;
    const int bid  = blockIdx.x;
    const int kq   = bid & 3;        // split-K quarter
    const int ot   = bid >> 2;       // o-tile
    const int o0   = ot * 16;
    const int orow = o0 + col;
    const int k0   = kq * 1024 + wv * 256;   // wave's 256-k slab (2 groups)
    const int g0   = k0 >> 7;
    const bool mvalid = (col < 8);

    float2 sg = *(const float2*)(scales + (size_t)orow * NGRP + g0);
    float2 zg = *(const float2*)(zeros  + (size_t)orow * NGRP + g0);

    // ---- x fragments up-front, distinct regs per sub-slab (no aliasing) ----
    f16x8 af[4][2];
    const f16* xcol = xh + (size_t)col * IN_F + k0 + kg * 8;
    #pragma unroll
    for (int ss = 0; ss < 4; ++ss) {
        if (mvalid) {
            af[ss][0] = *(const f16x8*)(xcol + ss * 64);
            af[ss][1] = *(const f16x8*)(xcol + ss * 64 + 32);
        } else {
            af[ss][0] = (f16x8){0,0,0,0,0,0,0,0};
            af[ss][1] = (f16x8){0,0,0,0,0,0,0,0};
        }
    }

    const char* wb   = (const char*)wq;
    const int   coff = (lane & 7) * 16;

    // stage sub-slab ss weights into buffer ss&1: exactly 2 vmem ops
    auto stageW = [&](int ss) {
        const int b = ss & 1;
        #pragma unroll
        for (int j = 0; j < 2; ++j) {
            const int r = j * 8 + (lane >> 3);
            const char* src = wb + (size_t)(o0 + r) * 8192
                              + (size_t)(k0 + ss * 64) * 2
                              + (coff ^ ((r & 7) << 4));
            __builtin_amdgcn_global_load_lds(
                (const __attribute__((address_space(1))) void*)src,
                (__attribute__((address_space(3))) void*)&wlds[wv][b][j * 1024],
                16, 0, 0);
        }
    };

    stageW(0); __builtin_amdgcn_sched_barrier(0);
    stageW(1); __builtin_amdgcn_sched_barrier(0);

    const unsigned rswz = (unsigned)((col & 7) << 4);
    f32x4 acc = {0.f, 0.f, 0.f, 0.f};

    #pragma unroll
    for (int ss = 0; ss < 4; ++ss) {
        // stageW(ss) complete; stageW(ss+1)'s 2 ops stay in flight.
        // (x/sg/zg loads are all OLDER than stageW(1), so vmcnt(2) drains
        //  them too — counts stay exact.)
        if (ss < 3) asm volatile("s_waitcnt vmcnt(2)" ::: "memory");
        else        asm volatile("s_waitcnt vmcnt(0)" ::: "memory");
        __builtin_amdgcn_sched_barrier(0);

        const unsigned char* buf = &wlds[wv][ss & 1][0];
        const int4 qa = *(const int4*)(buf + (col * 128 + ((     kg * 16) ^ rswz)));
        const int4 qb = *(const int4*)(buf + (col * 128 + ((64 + kg * 16) ^ rswz)));

        // ds_reads landed before this buffer is re-staged (rule #18/#21)
        asm volatile("s_waitcnt lgkmcnt(0)" ::: "memory");
        __builtin_amdgcn_sched_barrier(0);
        if (ss < 2) { stageW(ss + 2); __builtin_amdgcn_sched_barrier(0); }

        const f16x2 s2 = bcast((ss < 2) ? sg.x : sg.y);
        const f16x2 z2 = bcast((ss < 2) ? zg.x : zg.y);
        u32x4 ba = {dq2((unsigned)qa.x, s2, z2), dq2((unsigned)qa.y, s2, z2),
                    dq2((unsigned)qa.z, s2, z2), dq2((unsigned)qa.w, s2, z2)};
        u32x4 bb = {dq2((unsigned)qb.x, s2, z2), dq2((unsigned)qb.y, s2, z2),
                    dq2((unsigned)qb.z, s2, z2), dq2((unsigned)qb.w, s2, z2)};
        acc = __builtin_amdgcn_mfma_f32_16x16x32_f16(af[ss][0],
                __builtin_bit_cast(f16x8, ba), acc, 0, 0, 0);
        acc = __builtin_amdgcn_mfma_f32_16x16x32_f16(af[ss][1],
                __builtin_bit_cast(f16x8, bb), acc, 0, 0, 0);
    }

    // cross-wave reduce (LDS reuse; each wave writes only its own region)
    *(f32x4*)&wlds[wv][0][lane * 16] = acc;
    __syncthreads();

    if (tid < 32) {   // rows 0..7: mbase = (tid>>4)*4 in {0,4}
        f32x4 ssum = *(const f32x4*)&wlds[0][0][tid * 16];
        #pragma unroll
        for (int w = 1; w < 4; ++w)
            ssum += *(const f32x4*)&wlds[w][0][tid * 16];
        const int n = tid & 15;
        const int mbase = (tid >> 4) * 4;
        float* plane = wsf + (size_t)kq * PLANE;
        #pragma unroll
        for (int i = 0; i < 4; ++i)
            plane[(size_t)(mbase + i) * OUT_F + o0 + n] = ssum[i];
    }
}

// out[idx] = bias[o] + sum of 4 split-K planes
__global__ __launch_bounds__(256)
void reduce_kernel(const float* __restrict__ wsf,
                   const float* __restrict__ bias,
                   float* __restrict__ out)
{
    const int idx = blockIdx.x * 256 + threadIdx.x;   // 0..88063
    const int o = idx % OUT_F;
    out[idx] = bias[o] + wsf[idx] + wsf[PLANE + idx]
             + wsf[2 * PLANE + idx] + wsf[3 * PLANE + idx];
}

// ---------------- fallback (R5-style, used only if ws too small) ------------
__global__ __launch_bounds__(256, 4)
void qlin_kernel(const int* __restrict__ wq,
                 const float* __restrict__ scales,
                 const float* __restrict__ zeros,
                 const float* __restrict__ bias,
                 const float* __restrict__ xf,
                 float* __restrict__ out)
{
    __shared__ unsigned char wlds[2][16][1024];
    __shared__ f32x4 red[4][64];

    const int tid  = threadIdx.x;
    const int wv   = tid >> 6;
    const int lane = tid & 63;
    const int col  = lane & 15;
    const int kg   = lane >> 4;
    const int o0   = blockIdx.x * 16;
    const int orow = o0 + col;
    const bool mvalid = (col < 8);

    f16x2 sp[8], zp[8];
    #pragma unroll
    for (int s = 0; s < 8; ++s) {
        sp[s] = bcast(scales[(size_t)orow * NGRP + s * 4 + wv]);
        zp[s] = bcast(zeros [(size_t)orow * NGRP + s * 4 + wv]);
    }

    const char* wtile = (const char*)wq + (size_t)o0 * 8192;
    auto stage = [&](int sl, int bufi) {
        #pragma unroll
        for (int c = 0; c < 4; ++c) {
            const int r = 4 * wv + c;
            const char* src = wtile + (size_t)r * 8192 + sl * 1024
                              + ((lane * 16) ^ ((r & 7) << 4));
            __builtin_amdgcn_global_load_lds(
                (const __attribute__((address_space(1))) void*)src,
                (__attribute__((address_space(3))) void*)&wlds[bufi][r][0],
                16, 0, 0);
        }
    };

    stage(0, 0);
    stage(1, 1);

    const float* xfcol = xf + (size_t)col * IN_F;
    const unsigned swz = (unsigned)((col & 7) << 4);
    f32x4 acc = {0.f, 0.f, 0.f, 0.f};

    #pragma unroll
    for (int s = 0; s < 8; ++s) {
        asm volatile("s_waitcnt vmcnt(0)" ::: "memory");
        __builtin_amdgcn_s_barrier();
        asm volatile("" ::: "memory");

        const f16x2 s2 = sp[s], z2 = zp[s];
        #pragma unroll
        for (int t = 0; t < 4; ++t) {
            const int k = s * 512 + wv * 128 + t * 32 + kg * 8;
            f16x8 af = (f16x8){0,0,0,0,0,0,0,0};
            if (mvalid) {
                float4 a0 = *(const float4*)(xfcol + k);
                float4 a1 = *(const float4*)(xfcol + k + 4);
                af = (f16x8){(f16)a0.x,(f16)a0.y,(f16)a0.z,(f16)a0.w,
                             (f16)a1.x,(f16)a1.y,(f16)a1.z,(f16)a1.w};
            }
            const unsigned off = ((unsigned)(wv * 256 + t * 64 + kg * 16)) ^ swz;
            const int4 q = *(const int4*)&wlds[s & 1][col][off];
            u32x4 bw = {dq2((unsigned)q.x, s2, z2),
                        dq2((unsigned)q.y, s2, z2),
                        dq2((unsigned)q.z, s2, z2),
                        dq2((unsigned)q.w, s2, z2)};
            f16x8 bfr = __builtin_bit_cast(f16x8, bw);
            acc = __builtin_amdgcn_mfma_f32_16x16x32_f16(af, bfr, acc, 0, 0, 0);
        }

        asm volatile("" ::: "memory");
        __builtin_amdgcn_s_barrier();
        if (s < 6) stage(s + 2, s & 1);
    }

    red[wv][lane] = acc;
    __syncthreads();

    if (tid < 64) {
        f32x4 ssum = red[0][tid];
        #pragma unroll
        for (int w = 1; w < 4; ++w) ssum += red[w][tid];
        const int n = tid & 15;
        const float bb = bias[o0 + n];
        const int mbase = (tid >> 4) * 4;
        if (mbase < 8) {
            #pragma unroll
            for (int i = 0; i < 4; ++i)
                out[(size_t)(mbase + i) * OUT_F + o0 + n] = ssum[i] + bb;
        }
    }
}

extern "C" void kernel_launch(void* const* d_in, const int* in_sizes, int n_in,
                              void* d_out, int out_size, void* d_ws, size_t ws_size,
                              hipStream_t stream) {
    const float* x  = (const float*)d_in[0];
    const int*   wq = (const int*)d_in[1];
    const float* sc = (const float*)d_in[2];
    const float* zr = (const float*)d_in[3];
    const float* bs = (const float*)d_in[4];
    float* out = (float*)d_out;
    (void)in_sizes; (void)n_in;

    const size_t planes_b = (size_t)4 * PLANE * sizeof(float);
    const size_t xh_b     = (size_t)8 * IN_F * sizeof(f16);

    if (ws_size >= planes_b + xh_b) {
        float* wsf = (float*)d_ws;
        f16*   xh  = (f16*)((char*)d_ws + planes_b);
        xprep_kernel<<<(8 * IN_F) / (256 * 4), 256, 0, stream>>>(x, xh);
        qlin_pipe<<<NTILE * 4, 256, 0, stream>>>(wq, sc, zr, xh, wsf);
        reduce_kernel<<<PLANE / 256, 256, 0, stream>>>(wsf, bs, out);
    } else {
        qlin_kernel<<<NTILE, 256, 0, stream>>>(wq, sc, zr, bs, x, out);
    }
}